// Round 7
// baseline (140.803 us; speedup 1.0000x reference)
//
#include <hip/hip_runtime.h>
#include <hip/hip_bf16.h>
#include <stdint.h>

#define B_ 4096
#define L_ 80
#define V_ 256
#define H_ 512
#define BT 16
#define HP 520  // padded LDS row stride (elems), 16B-aligned

typedef __attribute__((ext_vector_type(4))) float f32x4;
typedef __attribute__((ext_vector_type(8))) short bf16x8;
typedef __attribute__((ext_vector_type(8))) unsigned short ushort8;

static __device__ __forceinline__ unsigned short f2bf(float x) {
  union { float f; unsigned int u; } a;
  a.f = x;
  unsigned int r = a.u + 0x7fffu + ((a.u >> 16) & 1u);
  return (unsigned short)(r >> 16);
}
static __device__ __forceinline__ float bf2f(unsigned short u) {
  union { unsigned int i; float f; } a;
  a.i = ((unsigned int)u) << 16;
  return a.f;
}

// ---------------------------------------------------------------------------
// Kernel 0 (prep): blocks [0, 5120): W1 f32 -> W1b bf16 (8 elems/thread);
//                  blocks [5120, 5376): W2 -> W2T bf16 (LDS-tiled transpose).
// Pure streaming: ~68 MB total -> ~11 us at 6 TB/s (HBM roofline).
// ---------------------------------------------------------------------------
__global__ __launch_bounds__(256) void prep(
    const float* __restrict__ W2, const float* __restrict__ W1,
    unsigned short* __restrict__ W2T, unsigned short* __restrict__ W1b) {
  const int bid = blockIdx.x;
  if (bid < 5120) {
    const size_t i8 = ((size_t)bid * 256 + threadIdx.x) * 8;
    f32x4 v0 = *reinterpret_cast<const f32x4*>(W1 + i8);
    f32x4 v1 = *reinterpret_cast<const f32x4*>(W1 + i8 + 4);
    ushort8 o;
    o[0] = f2bf(v0[0]); o[1] = f2bf(v0[1]); o[2] = f2bf(v0[2]); o[3] = f2bf(v0[3]);
    o[4] = f2bf(v1[0]); o[5] = f2bf(v1[1]); o[6] = f2bf(v1[2]); o[7] = f2bf(v1[3]);
    *reinterpret_cast<ushort8*>(W1b + i8) = o;
  } else {
    __shared__ float tile[32][33];
    const int tb = bid - 5120;
    const int ti = tb & 15, tj = tb >> 4;
    const int r = threadIdx.x >> 5, c = threadIdx.x & 31;
#pragma unroll
    for (int rr = r; rr < 32; rr += 8)
      tile[rr][c] = W2[(size_t)(ti * 32 + rr) * H_ + tj * 32 + c];
    __syncthreads();
#pragma unroll
    for (int rr = r; rr < 32; rr += 8)
      W2T[(size_t)(tj * 32 + rr) * H_ + ti * 32 + c] = f2bf(tile[c][rr]);
  }
}

// ---------------------------------------------------------------------------
// Kernel 1 (fused): gather-sum(bf16 W1) + b1 + relu -> h-slab in LDS, then
// 16x512 @ 512x512 bf16 MFMA GEMM + b2 + relu -> out.
// 256 blocks x 512 threads (8 waves). PROVEN R4 STRUCTURE: wave w owns rows
// 2w,2w+1 -> paired-row L2 reuse per l-slice + 2 independent accum chains.
// unroll 8: 16 outstanding 16B loads/wave for deeper miss overlap.
// GEMM: wave w owns output cols [w*64, w*64+64) (4 frags, K=512), W2T
// streamed from L2 (512 KB/block, at L2 roofline).
// C/D mapping: col=lane&15, row=(lane>>4)*4+reg (m89-verified, R1-R5).
// ---------------------------------------------------------------------------
__global__ __launch_bounds__(512) void fused_gather_gemm(
    const int* __restrict__ msg, const unsigned short* __restrict__ W1b,
    const float* __restrict__ b1, const unsigned short* __restrict__ W2T,
    const float* __restrict__ b2, float* __restrict__ out) {
  __shared__ int offs[BT * L_];
  __shared__ unsigned short hl[BT * HP];

  const int t = threadIdx.x;
  const int w = t >> 6;       // 0..7
  const int lane = t & 63;
  const int b0 = blockIdx.x * BT;

  for (int i = t; i < BT * L_; i += 512) {
    int b = i / L_, l = i - b * L_;
    offs[i] = (l * V_ + msg[(b0 + b) * L_ + l]) * H_;
  }
  __syncthreads();

  // ---- gather phase: wave w accumulates rows 2w, 2w+1 ----
  const int r0 = 2 * w, r1 = r0 + 1;
  const int c8 = lane * 8;
  float a0[8] = {}, a1[8] = {};

#pragma unroll 8
  for (int l = 0; l < L_; ++l) {
    int o0 = __builtin_amdgcn_readfirstlane(offs[r0 * L_ + l]);
    int o1 = __builtin_amdgcn_readfirstlane(offs[r1 * L_ + l]);
    ushort8 v0 = *reinterpret_cast<const ushort8*>(W1b + o0 + c8);
    ushort8 v1 = *reinterpret_cast<const ushort8*>(W1b + o1 + c8);
#pragma unroll
    for (int j = 0; j < 8; ++j) {
      a0[j] += bf2f(v0[j]);
      a1[j] += bf2f(v1[j]);
    }
  }

  ushort8 h0, h1;
#pragma unroll
  for (int j = 0; j < 8; ++j) {
    float bias = b1[c8 + j];
    float x0 = a0[j] + bias, x1 = a1[j] + bias;
    h0[j] = f2bf(x0 > 0.f ? x0 : 0.f);
    h1[j] = f2bf(x1 > 0.f ? x1 : 0.f);
  }
  *reinterpret_cast<ushort8*>(&hl[r0 * HP + c8]) = h0;
  *reinterpret_cast<ushort8*>(&hl[r1 * HP + c8]) = h1;
  __syncthreads();

  // ---- GEMM phase: wave w -> output cols [w*64, w*64+64) ----
  const int lr = lane & 15;
  const int lq = lane >> 4;
  f32x4 acc[4] = {};

  const unsigned short* bp = W2T + (size_t)(w * 64 + lr) * H_ + lq * 8;

#pragma unroll 4
  for (int kt = 0; kt < H_ / 32; ++kt) {
    bf16x8 a = *reinterpret_cast<const bf16x8*>(&hl[lr * HP + kt * 32 + lq * 8]);
#pragma unroll
    for (int ni = 0; ni < 4; ++ni) {
      bf16x8 b = *reinterpret_cast<const bf16x8*>(bp + (size_t)ni * 16 * H_ + kt * 32);
      acc[ni] = __builtin_amdgcn_mfma_f32_16x16x32_bf16(a, b, acc[ni], 0, 0, 0);
    }
  }

#pragma unroll
  for (int ni = 0; ni < 4; ++ni) {
    const int n = w * 64 + ni * 16 + lr;
    const float bias = b2[n];
#pragma unroll
    for (int r = 0; r < 4; ++r) {
      const int m = lq * 4 + r;
      float v = acc[ni][r] + bias;
      out[(size_t)(b0 + m) * H_ + n] = v > 0.f ? v : 0.f;
    }
  }
}

// ---------------------------------------------------------------------------
extern "C" void kernel_launch(void* const* d_in, const int* in_sizes, int n_in,
                              void* d_out, int out_size, void* d_ws, size_t ws_size,
                              hipStream_t stream) {
  const int* msg   = (const int*)d_in[0];
  const float* W1  = (const float*)d_in[1];
  const float* b1  = (const float*)d_in[2];
  const float* W2  = (const float*)d_in[3];
  const float* b2  = (const float*)d_in[4];
  float* out = (float*)d_out;

  unsigned short* W2T = (unsigned short*)d_ws;                        // 512 KB
  unsigned short* W1b = (unsigned short*)((char*)d_ws + (size_t)H_ * H_ * 2);

  hipLaunchKernelGGL(prep, dim3(5120 + 256), dim3(256), 0, stream,
                     W2, W1, W2T, W1b);
  hipLaunchKernelGGL(fused_gather_gemm, dim3(B_ / BT), dim3(512), 0, stream,
                     msg, W1b, b1, W2T, b2, out);
}

// Round 8
// 131.954 us; speedup vs baseline: 1.0671x; 1.0671x over previous
//
#include <hip/hip_runtime.h>
#include <hip/hip_bf16.h>
#include <stdint.h>

#define B_ 4096
#define L_ 80
#define V_ 256
#define H_ 512
#define BT 16
#define HP 520  // padded LDS row stride (elems), 16B-aligned

typedef __attribute__((ext_vector_type(4))) float f32x4;
typedef __attribute__((ext_vector_type(8))) short bf16x8;
typedef __attribute__((ext_vector_type(8))) unsigned short ushort8;

static __device__ __forceinline__ unsigned short f2bf(float x) {
  union { float f; unsigned int u; } a;
  a.f = x;
  unsigned int r = a.u + 0x7fffu + ((a.u >> 16) & 1u);
  return (unsigned short)(r >> 16);
}
static __device__ __forceinline__ float bf2f(unsigned short u) {
  union { unsigned int i; float f; } a;
  a.i = ((unsigned int)u) << 16;
  return a.f;
}

// ---------------------------------------------------------------------------
// Kernel 0 (prep): blocks [0, 5120): W1 f32 -> W1b bf16 (8 elems/thread);
//                  blocks [5120, 5376): W2 -> W2T bf16 (LDS-tiled transpose).
// Pure streaming: ~68 MB -> ~11 us at 6 TB/s (HBM roofline).
// ---------------------------------------------------------------------------
__global__ __launch_bounds__(256) void prep(
    const float* __restrict__ W2, const float* __restrict__ W1,
    unsigned short* __restrict__ W2T, unsigned short* __restrict__ W1b) {
  const int bid = blockIdx.x;
  if (bid < 5120) {
    const size_t i8 = ((size_t)bid * 256 + threadIdx.x) * 8;
    f32x4 v0 = *reinterpret_cast<const f32x4*>(W1 + i8);
    f32x4 v1 = *reinterpret_cast<const f32x4*>(W1 + i8 + 4);
    ushort8 o;
    o[0] = f2bf(v0[0]); o[1] = f2bf(v0[1]); o[2] = f2bf(v0[2]); o[3] = f2bf(v0[3]);
    o[4] = f2bf(v1[0]); o[5] = f2bf(v1[1]); o[6] = f2bf(v1[2]); o[7] = f2bf(v1[3]);
    *reinterpret_cast<ushort8*>(W1b + i8) = o;
  } else {
    __shared__ float tile[32][33];
    const int tb = bid - 5120;
    const int ti = tb & 15, tj = tb >> 4;
    const int r = threadIdx.x >> 5, c = threadIdx.x & 31;
#pragma unroll
    for (int rr = r; rr < 32; rr += 8)
      tile[rr][c] = W2[(size_t)(ti * 32 + rr) * H_ + tj * 32 + c];
    __syncthreads();
#pragma unroll
    for (int rr = r; rr < 32; rr += 8)
      W2T[(size_t)(tj * 32 + rr) * H_ + ti * 32 + c] = f2bf(tile[c][rr]);
  }
}

// ---------------------------------------------------------------------------
// Kernel 1 (fused): gather-sum(bf16 W1) + b1 + relu -> h-slab in LDS, then
// 16x512 @ 512x512 bf16 MFMA GEMM + b2 + relu -> out.
// 256 blocks x 1024 threads (16 waves = 4/SIMD). SPLIT-L STRUCTURE:
// wave pair (w, w+8) both own rows (2wq, 2wq+1); half 0 gathers l in [0,40),
// half 1 gathers l in [40,80). Keeps R4's paired-row locality + same per-block
// footprint (disjoint l -> disjoint W1 slices) while doubling wave-level MLP
// and halving each wave's serial chain (R7 lesson: ILP unrolling gave no MLP,
// VGPR stayed 32 -- parallelism must come from waves).
// Partial sums reduced via SoA LDS pf[row][j][lane] (conflict-free).
// GEMM: wave w owns output cols [w*32, w*32+32) (2 frags, K=512; R5-proven).
// C/D mapping: col=lane&15, row=(lane>>4)*4+reg (m89-verified, R1-R7).
// ---------------------------------------------------------------------------
__global__ __launch_bounds__(1024) void fused_gather_gemm(
    const int* __restrict__ msg, const unsigned short* __restrict__ W1b,
    const float* __restrict__ b1, const unsigned short* __restrict__ W2T,
    const float* __restrict__ b2, float* __restrict__ out) {
  __shared__ int offs[BT * L_];            // 5 KB
  __shared__ float pf[BT * H_];            // 32 KB partials, [row][j][lane]
  __shared__ unsigned short hl[BT * HP];   // 16.6 KB

  const int t = threadIdx.x;
  const int w = t >> 6;        // 0..15
  const int lane = t & 63;
  const int b0 = blockIdx.x * BT;

  for (int i = t; i < BT * L_; i += 1024) {
    int b = i / L_, l = i - b * L_;
    offs[i] = (l * V_ + msg[(b0 + b) * L_ + l]) * H_;
  }
  __syncthreads();

  // ---- gather phase: wave pair (wq, half) ----
  const int wq = w & 7, half = w >> 3;
  const int r0 = 2 * wq, r1 = r0 + 1;
  const int c8 = lane * 8;
  const int l0 = half * (L_ / 2);

  float a0[8] = {}, a1[8] = {};
#pragma unroll 4
  for (int l = l0; l < l0 + L_ / 2; ++l) {
    int o0 = __builtin_amdgcn_readfirstlane(offs[r0 * L_ + l]);
    int o1 = __builtin_amdgcn_readfirstlane(offs[r1 * L_ + l]);
    ushort8 v0 = *reinterpret_cast<const ushort8*>(W1b + o0 + c8);
    ushort8 v1 = *reinterpret_cast<const ushort8*>(W1b + o1 + c8);
#pragma unroll
    for (int j = 0; j < 8; ++j) {
      a0[j] += bf2f(v0[j]);
      a1[j] += bf2f(v1[j]);
    }
  }

  if (half == 1) {
#pragma unroll
    for (int j = 0; j < 8; ++j) {
      pf[r0 * H_ + j * 64 + lane] = a0[j];
      pf[r1 * H_ + j * 64 + lane] = a1[j];
    }
  }
  __syncthreads();

  if (half == 0) {
    ushort8 h0, h1;
#pragma unroll
    for (int j = 0; j < 8; ++j) {
      float bias = b1[c8 + j];
      float x0 = a0[j] + pf[r0 * H_ + j * 64 + lane] + bias;
      float x1 = a1[j] + pf[r1 * H_ + j * 64 + lane] + bias;
      h0[j] = f2bf(x0 > 0.f ? x0 : 0.f);
      h1[j] = f2bf(x1 > 0.f ? x1 : 0.f);
    }
    *reinterpret_cast<ushort8*>(&hl[r0 * HP + c8]) = h0;
    *reinterpret_cast<ushort8*>(&hl[r1 * HP + c8]) = h1;
  }
  __syncthreads();

  // ---- GEMM phase: wave w -> output cols [w*32, w*32+32) ----
  const int lr = lane & 15;
  const int lq = lane >> 4;
  f32x4 acc[2] = {};

  const unsigned short* bp = W2T + (size_t)(w * 32 + lr) * H_ + lq * 8;

#pragma unroll 4
  for (int kt = 0; kt < H_ / 32; ++kt) {
    bf16x8 a = *reinterpret_cast<const bf16x8*>(&hl[lr * HP + kt * 32 + lq * 8]);
#pragma unroll
    for (int ni = 0; ni < 2; ++ni) {
      bf16x8 b = *reinterpret_cast<const bf16x8*>(bp + (size_t)ni * 16 * H_ + kt * 32);
      acc[ni] = __builtin_amdgcn_mfma_f32_16x16x32_bf16(a, b, acc[ni], 0, 0, 0);
    }
  }

#pragma unroll
  for (int ni = 0; ni < 2; ++ni) {
    const int n = w * 32 + ni * 16 + lr;
    const float bias = b2[n];
#pragma unroll
    for (int r = 0; r < 4; ++r) {
      const int m = lq * 4 + r;
      float v = acc[ni][r] + bias;
      out[(size_t)(b0 + m) * H_ + n] = v > 0.f ? v : 0.f;
    }
  }
}

// ---------------------------------------------------------------------------
extern "C" void kernel_launch(void* const* d_in, const int* in_sizes, int n_in,
                              void* d_out, int out_size, void* d_ws, size_t ws_size,
                              hipStream_t stream) {
  const int* msg   = (const int*)d_in[0];
  const float* W1  = (const float*)d_in[1];
  const float* b1  = (const float*)d_in[2];
  const float* W2  = (const float*)d_in[3];
  const float* b2  = (const float*)d_in[4];
  float* out = (float*)d_out;

  unsigned short* W2T = (unsigned short*)d_ws;                        // 512 KB
  unsigned short* W1b = (unsigned short*)((char*)d_ws + (size_t)H_ * H_ * 2);

  hipLaunchKernelGGL(prep, dim3(5120 + 256), dim3(256), 0, stream,
                     W2, W1, W2T, W1b);
  hipLaunchKernelGGL(fused_gather_gemm, dim3(B_ / BT), dim3(1024), 0, stream,
                     msg, W1b, b1, W2T, b2, out);
}

// Round 9
// 131.076 us; speedup vs baseline: 1.0742x; 1.0067x over previous
//
#include <hip/hip_runtime.h>
#include <hip/hip_bf16.h>
#include <stdint.h>

#define B_ 4096
#define L_ 80
#define V_ 256
#define H_ 512
#define BT 16
#define HP 520  // padded LDS row stride (elems), 16B-aligned

typedef __attribute__((ext_vector_type(4))) float f32x4;
typedef __attribute__((ext_vector_type(8))) short bf16x8;
typedef __attribute__((ext_vector_type(8))) unsigned short ushort8;

static __device__ __forceinline__ unsigned short f2bf(float x) {
  union { float f; unsigned int u; } a;
  a.f = x;
  unsigned int r = a.u + 0x7fffu + ((a.u >> 16) & 1u);
  return (unsigned short)(r >> 16);
}
static __device__ __forceinline__ float bf2f(unsigned short u) {
  union { unsigned int i; float f; } a;
  a.i = ((unsigned int)u) << 16;
  return a.f;
}

// ---------------------------------------------------------------------------
// Kernel 0 (prep): blocks [0, 5120): W1 f32 -> W1b bf16 (8 elems/thread);
//                  blocks [5120, 5376): W2 -> W2T bf16 (LDS-tiled transpose).
// Pure streaming: ~68 MB -> ~11 us at 6 TB/s (HBM roofline).
// ---------------------------------------------------------------------------
__global__ __launch_bounds__(256) void prep(
    const float* __restrict__ W2, const float* __restrict__ W1,
    unsigned short* __restrict__ W2T, unsigned short* __restrict__ W1b) {
  const int bid = blockIdx.x;
  if (bid < 5120) {
    const size_t i8 = ((size_t)bid * 256 + threadIdx.x) * 8;
    f32x4 v0 = *reinterpret_cast<const f32x4*>(W1 + i8);
    f32x4 v1 = *reinterpret_cast<const f32x4*>(W1 + i8 + 4);
    ushort8 o;
    o[0] = f2bf(v0[0]); o[1] = f2bf(v0[1]); o[2] = f2bf(v0[2]); o[3] = f2bf(v0[3]);
    o[4] = f2bf(v1[0]); o[5] = f2bf(v1[1]); o[6] = f2bf(v1[2]); o[7] = f2bf(v1[3]);
    *reinterpret_cast<ushort8*>(W1b + i8) = o;
  } else {
    __shared__ float tile[32][33];
    const int tb = bid - 5120;
    const int ti = tb & 15, tj = tb >> 4;
    const int r = threadIdx.x >> 5, c = threadIdx.x & 31;
#pragma unroll
    for (int rr = r; rr < 32; rr += 8)
      tile[rr][c] = W2[(size_t)(ti * 32 + rr) * H_ + tj * 32 + c];
    __syncthreads();
#pragma unroll
    for (int rr = r; rr < 32; rr += 8)
      W2T[(size_t)(tj * 32 + rr) * H_ + ti * 32 + c] = f2bf(tile[c][rr]);
  }
}

// ---------------------------------------------------------------------------
// Kernel 1 (fused): gather-sum(bf16 W1) + b1 + relu -> h-slab in LDS, then
// 16x512 @ 512x512 bf16 MFMA GEMM + b2 + relu -> out.
// 256 blocks x 1024 threads (16 waves). SPLIT-L (R8-proven): wave pair
// (w, w+8) owns rows (2wq, 2wq+1); half 0 gathers l in [0,40), half 1
// l in [40,80). NEW: explicit 4-slot software-pipelined gather (named
// register slots A-D, 8 row-loads in flight vs compiler's ~2-4; R7/R8
// showed #pragma unroll alone never materializes the pipeline).
// Partials reduced via SoA LDS pf[row][j][lane] (conflict-free).
// GEMM: wave w owns output cols [w*32, w*32+32) (2 frags, K=512).
// C/D mapping: col=lane&15, row=(lane>>4)*4+reg (m89-verified, R1-R8).
// ---------------------------------------------------------------------------
__global__ __launch_bounds__(1024) void fused_gather_gemm(
    const int* __restrict__ msg, const unsigned short* __restrict__ W1b,
    const float* __restrict__ b1, const unsigned short* __restrict__ W2T,
    const float* __restrict__ b2, float* __restrict__ out) {
  __shared__ int offs[BT * L_];            // 5 KB
  __shared__ float pf[BT * H_];            // 32 KB partials, [row][j][lane]
  __shared__ unsigned short hl[BT * HP];   // 16.6 KB

  const int t = threadIdx.x;
  const int w = t >> 6;        // 0..15
  const int lane = t & 63;
  const int b0 = blockIdx.x * BT;

  for (int i = t; i < BT * L_; i += 1024) {
    int b = i / L_, l = i - b * L_;
    offs[i] = (l * V_ + msg[(b0 + b) * L_ + l]) * H_;
  }
  __syncthreads();

  // ---- gather phase: wave pair (wq, half), 4-slot pipelined ----
  const int wq = w & 7, half = w >> 3;
  const int r0 = 2 * wq, r1 = r0 + 1;
  const int c8 = lane * 8;
  const int l0 = half * (L_ / 2);

  float a0[8] = {}, a1[8] = {};
  ushort8 vA0, vA1, vB0, vB1, vC0, vC1, vD0, vD1;

#define LOADP(S, l_)                                                        \
  {                                                                         \
    int o0_ = __builtin_amdgcn_readfirstlane(offs[r0 * L_ + (l_)]);         \
    int o1_ = __builtin_amdgcn_readfirstlane(offs[r1 * L_ + (l_)]);         \
    v##S##0 = *reinterpret_cast<const ushort8*>(W1b + o0_ + c8);            \
    v##S##1 = *reinterpret_cast<const ushort8*>(W1b + o1_ + c8);            \
  }
#define ACCP(S)                                                             \
  {                                                                         \
    _Pragma("unroll") for (int j = 0; j < 8; ++j) {                         \
      a0[j] += bf2f(v##S##0[j]);                                            \
      a1[j] += bf2f(v##S##1[j]);                                            \
    }                                                                       \
  }

  LOADP(A, l0 + 0); LOADP(B, l0 + 1); LOADP(C, l0 + 2); LOADP(D, l0 + 3);
  for (int i = 0; i < 9; ++i) {  // 9*4 = 36 consume/reload steps
    const int lb = l0 + 4 + i * 4;
    ACCP(A); LOADP(A, lb + 0);
    ACCP(B); LOADP(B, lb + 1);
    ACCP(C); LOADP(C, lb + 2);
    ACCP(D); LOADP(D, lb + 3);
  }
  ACCP(A); ACCP(B); ACCP(C); ACCP(D);  // epilogue: l0+36..l0+39
#undef LOADP
#undef ACCP

  if (half == 1) {
#pragma unroll
    for (int j = 0; j < 8; ++j) {
      pf[r0 * H_ + j * 64 + lane] = a0[j];
      pf[r1 * H_ + j * 64 + lane] = a1[j];
    }
  }
  __syncthreads();

  if (half == 0) {
    ushort8 h0, h1;
#pragma unroll
    for (int j = 0; j < 8; ++j) {
      float bias = b1[c8 + j];
      float x0 = a0[j] + pf[r0 * H_ + j * 64 + lane] + bias;
      float x1 = a1[j] + pf[r1 * H_ + j * 64 + lane] + bias;
      h0[j] = f2bf(x0 > 0.f ? x0 : 0.f);
      h1[j] = f2bf(x1 > 0.f ? x1 : 0.f);
    }
    *reinterpret_cast<ushort8*>(&hl[r0 * HP + c8]) = h0;
    *reinterpret_cast<ushort8*>(&hl[r1 * HP + c8]) = h1;
  }
  __syncthreads();

  // ---- GEMM phase: wave w -> output cols [w*32, w*32+32) ----
  const int lr = lane & 15;
  const int lq = lane >> 4;
  f32x4 acc[2] = {};

  const unsigned short* bp = W2T + (size_t)(w * 32 + lr) * H_ + lq * 8;

#pragma unroll 4
  for (int kt = 0; kt < H_ / 32; ++kt) {
    bf16x8 a = *reinterpret_cast<const bf16x8*>(&hl[lr * HP + kt * 32 + lq * 8]);
#pragma unroll
    for (int ni = 0; ni < 2; ++ni) {
      bf16x8 b = *reinterpret_cast<const bf16x8*>(bp + (size_t)ni * 16 * H_ + kt * 32);
      acc[ni] = __builtin_amdgcn_mfma_f32_16x16x32_bf16(a, b, acc[ni], 0, 0, 0);
    }
  }

#pragma unroll
  for (int ni = 0; ni < 2; ++ni) {
    const int n = w * 32 + ni * 16 + lr;
    const float bias = b2[n];
#pragma unroll
    for (int r = 0; r < 4; ++r) {
      const int m = lq * 4 + r;
      float v = acc[ni][r] + bias;
      out[(size_t)(b0 + m) * H_ + n] = v > 0.f ? v : 0.f;
    }
  }
}

// ---------------------------------------------------------------------------
extern "C" void kernel_launch(void* const* d_in, const int* in_sizes, int n_in,
                              void* d_out, int out_size, void* d_ws, size_t ws_size,
                              hipStream_t stream) {
  const int* msg   = (const int*)d_in[0];
  const float* W1  = (const float*)d_in[1];
  const float* b1  = (const float*)d_in[2];
  const float* W2  = (const float*)d_in[3];
  const float* b2  = (const float*)d_in[4];
  float* out = (float*)d_out;

  unsigned short* W2T = (unsigned short*)d_ws;                        // 512 KB
  unsigned short* W1b = (unsigned short*)((char*)d_ws + (size_t)H_ * H_ * 2);

  hipLaunchKernelGGL(prep, dim3(5120 + 256), dim3(256), 0, stream,
                     W2, W1, W2T, W1b);
  hipLaunchKernelGGL(fused_gather_gemm, dim3(B_ / BT), dim3(1024), 0, stream,
                     msg, W1b, b1, W2T, b2, out);
}